// Round 5
// baseline (384.457 us; speedup 1.0000x reference)
//
#include <hip/hip_runtime.h>

// ---------------- graph preprocessing (bucketed counting sort) ----------------
// Buckets of 64 consecutive dst nodes. Exact CSR built with block-local writes.

static constexpr int NPB_SHIFT = 6;           // 64 nodes per bucket
static constexpr int NPB = 1 << NPB_SHIFT;
static constexpr int MAX_BKT = 1024;          // supports n <= 65536

__global__ __launch_bounds__(256) void zero_int_kernel(int* __restrict__ p, int n) {
    int i = blockIdx.x * blockDim.x + threadIdx.x;
    if (i < n) p[i] = 0;
}

// K2: per-block LDS-binned bucket counts -> global bcnt
__global__ __launch_bounds__(256) void bucket_count_kernel(const int* __restrict__ dst, int E,
                                                           int nbkt, int* __restrict__ bcnt) {
    __shared__ int lc[MAX_BKT];
    int tid = threadIdx.x;
    for (int i = tid; i < nbkt; i += 256) lc[i] = 0;
    __syncthreads();
    for (int e = blockIdx.x * 256 + tid; e < E; e += gridDim.x * 256)
        atomicAdd(&lc[dst[e] >> NPB_SHIFT], 1);
    __syncthreads();
    for (int i = tid; i < nbkt; i += 256)
        if (lc[i]) atomicAdd(&bcnt[i], lc[i]);
}

// K3: single-block exclusive scan of bcnt -> bbase[0..nbkt], bcur; rowp[n] = E
__global__ __launch_bounds__(256) void bucket_scan_kernel(const int* __restrict__ bcnt, int nbkt,
                                                          int* __restrict__ bbase,
                                                          int* __restrict__ bcur,
                                                          int* __restrict__ rowp, int n) {
    __shared__ int wsum[4];
    int tid = threadIdx.x, lane = tid & 63, w = tid >> 6;
    int chunk = (nbkt + 255) / 256;
    int begin = tid * chunk;
    int end = begin + chunk; if (end > nbkt) end = nbkt;
    int s = 0;
    for (int i = begin; i < end; ++i) s += bcnt[i];
    int inc = s;
#pragma unroll
    for (int m = 1; m < 64; m <<= 1) {
        int u = __shfl_up(inc, m);
        if (lane >= m) inc += u;
    }
    if (lane == 63) wsum[w] = inc;
    __syncthreads();
    int off = 0;
    for (int i = 0; i < w; ++i) off += wsum[i];
    int run = off + inc - s;
    for (int i = begin; i < end; ++i) {
        bbase[i] = run; bcur[i] = run;
        run += bcnt[i];
    }
    if (tid == 255) { bbase[nbkt] = run; rowp[n] = run; }   // run == E
}

// K4: scatter (src,dst) pairs into bucket-partitioned regions
__global__ __launch_bounds__(256) void pair_scatter_kernel(const int* __restrict__ src,
                                                           const int* __restrict__ dst, int E,
                                                           int* __restrict__ bcur,
                                                           int2* __restrict__ part) {
    int e = blockIdx.x * 256 + threadIdx.x;
    if (e < E) {
        int d = dst[e];
        int pos = atomicAdd(&bcur[d >> NPB_SHIFT], 1);
        part[pos] = make_int2(src[e], d);
    }
}

// K5: one block per bucket: per-node counts (LDS), wave scan -> rowp/dinv,
// then localized scatter of csr within the block-exclusive region.
__global__ __launch_bounds__(256) void bucket_csr_kernel(const int2* __restrict__ part,
                                                         const int* __restrict__ bbase, int n,
                                                         int* __restrict__ rowp,
                                                         float* __restrict__ dinv,
                                                         int* __restrict__ csr) {
    __shared__ int lcnt[NPB];
    int b = blockIdx.x, tid = threadIdx.x;
    int node0 = b << NPB_SHIFT;
    int nloc = n - node0; if (nloc > NPB) nloc = NPB;
    int p0 = bbase[b], p1 = bbase[b + 1];
    if (tid < NPB) lcnt[tid] = 0;
    __syncthreads();
    for (int i = p0 + tid; i < p1; i += 256)
        atomicAdd(&lcnt[part[i].y & (NPB - 1)], 1);
    __syncthreads();
    if (tid < 64) {                       // wave 0: scan 64 counters
        int c = lcnt[tid];
        int inc = c;
#pragma unroll
        for (int m = 1; m < 64; m <<= 1) {
            int u = __shfl_up(inc, m);
            if (tid >= m) inc += u;
        }
        int base = p0 + inc - c;
        if (tid < nloc) {
            rowp[node0 + tid] = base;
            dinv[node0 + tid] = rsqrtf((float)(c + 1));    // +1 self-loop
        }
        lcnt[tid] = base;                 // becomes the scatter cursor
    }
    __syncthreads();
    for (int i = p0 + tid; i < p1; i += 256) {
        int2 pr = part[i];
        int pos = atomicAdd(&lcnt[pr.y & (NPB - 1)], 1);
        csr[pos] = pr.x;
    }
}

// ---------------- per-layer kernels ----------------

// Block-tiled GEMM: H[r][c] = epi(sum_k X[r][k] W[k][c])
// epi: +bias (BIAS), relu (RELU), * dinv[r] (SCALE) — in that order.
template <int K, int OUT, int BN, bool BIAS, bool RELU, bool SCALE>
__global__ __launch_bounds__(16 * (BN / 4)) void gemm_tile_kernel(
        const float* __restrict__ X, const float* __restrict__ W,
        const float* __restrict__ bias, const float* __restrict__ dinv,
        float* __restrict__ H, int n) {
    constexpr int BM = 64;
    constexpr int KB = (K > 64) ? 64 : K;
    constexpr int NTHR = 16 * (BN / 4);
    constexpr int KV = KB / 4;              // float4s per A row chunk

    __shared__ float At[KB][BM + 4];        // [k][r], stride 68 floats
    __shared__ float Bl[K][BN];

    const int tid = threadIdx.x;
    const int tx = tid % (BN / 4);
    const int ty = tid / (BN / 4);
    const int rb = blockIdx.x * BM;
    const int co = blockIdx.y * BN;

    // load B panel (W[:, co:co+BN]) once
    for (int i = tid; i < K * BN / 4; i += NTHR) {
        int k = i / (BN / 4);
        int c0 = (i % (BN / 4)) * 4;
        *reinterpret_cast<float4*>(&Bl[k][c0]) =
            *reinterpret_cast<const float4*>(&W[(size_t)k * OUT + co + c0]);
    }

    float acc[4][4] = {};

#pragma unroll
    for (int ch = 0; ch < K / KB; ++ch) {
        if (ch) __syncthreads();            // previous chunk's readers done
        // stage A chunk transposed
        for (int i = tid; i < BM * KV; i += NTHR) {
            int r = i / KV;
            int k0 = (i % KV) * 4;
            int rg = rb + r; if (rg > n - 1) rg = n - 1;     // clamp tail
            float4 xv = *reinterpret_cast<const float4*>(&X[(size_t)rg * K + ch * KB + k0]);
            At[k0 + 0][r] = xv.x;
            At[k0 + 1][r] = xv.y;
            At[k0 + 2][r] = xv.z;
            At[k0 + 3][r] = xv.w;
        }
        __syncthreads();

#pragma unroll 8
        for (int k = 0; k < KB; ++k) {
            float4 a = *reinterpret_cast<const float4*>(&At[k][ty * 4]);
            float4 b = *reinterpret_cast<const float4*>(&Bl[ch * KB + k][tx * 4]);
            acc[0][0] = fmaf(a.x, b.x, acc[0][0]); acc[0][1] = fmaf(a.x, b.y, acc[0][1]);
            acc[0][2] = fmaf(a.x, b.z, acc[0][2]); acc[0][3] = fmaf(a.x, b.w, acc[0][3]);
            acc[1][0] = fmaf(a.y, b.x, acc[1][0]); acc[1][1] = fmaf(a.y, b.y, acc[1][1]);
            acc[1][2] = fmaf(a.y, b.z, acc[1][2]); acc[1][3] = fmaf(a.y, b.w, acc[1][3]);
            acc[2][0] = fmaf(a.z, b.x, acc[2][0]); acc[2][1] = fmaf(a.z, b.y, acc[2][1]);
            acc[2][2] = fmaf(a.z, b.z, acc[2][2]); acc[2][3] = fmaf(a.z, b.w, acc[2][3]);
            acc[3][0] = fmaf(a.w, b.x, acc[3][0]); acc[3][1] = fmaf(a.w, b.y, acc[3][1]);
            acc[3][2] = fmaf(a.w, b.z, acc[3][2]); acc[3][3] = fmaf(a.w, b.w, acc[3][3]);
        }
    }

    float4 bv = make_float4(0.f, 0.f, 0.f, 0.f);
    if (BIAS) bv = *reinterpret_cast<const float4*>(&bias[co + tx * 4]);
    int r0 = rb + ty * 4;
#pragma unroll
    for (int i = 0; i < 4; ++i) {
        int r = r0 + i;
        if (r < n) {
            float4 o;
            o.x = acc[i][0]; o.y = acc[i][1]; o.z = acc[i][2]; o.w = acc[i][3];
            if (BIAS) { o.x += bv.x; o.y += bv.y; o.z += bv.z; o.w += bv.w; }
            if (RELU) {
                o.x = fmaxf(o.x, 0.f); o.y = fmaxf(o.y, 0.f);
                o.z = fmaxf(o.z, 0.f); o.w = fmaxf(o.w, 0.f);
            }
            if (SCALE) {
                float dv = dinv[r];
                o.x *= dv; o.y *= dv; o.z *= dv; o.w *= dv;
            }
            *reinterpret_cast<float4*>(&H[(size_t)r * OUT + co + tx * 4]) = o;
        }
    }
}

// One wave per node. Lanes split into EG = 64/(C/4) edge groups; each lane loads
// float4 of channels; 2x-unrolled edge loop for MLP. Cross-group shfl_xor reduce.
// o = dinv[d]*(H[d]+sum H[s]); if BIAS o += b; if RELU relu; if POST o *= dinv[d].
template <int C, bool RELU, bool HAS_BIAS, bool POST_SCALE>
__global__ __launch_bounds__(256) void aggregate_kernel(const float* __restrict__ H,
                                                        const int* __restrict__ row,
                                                        const int* __restrict__ csr_src,
                                                        const float* __restrict__ dinv,
                                                        const float* __restrict__ bias,
                                                        float* __restrict__ Y, int n) {
    constexpr int LPN = C / 4;        // lanes covering one row: 8 / 16
    constexpr int EG = 64 / LPN;      // edge groups: 8 / 4
    int wid = (blockIdx.x * blockDim.x + threadIdx.x) >> 6;
    if (wid >= n) return;             // wave-uniform exit
    int lane = threadIdx.x & 63;
    int g = lane / LPN;
    int c0 = (lane % LPN) * 4;
    const int node = wid;

    float4 acc = make_float4(0.f, 0.f, 0.f, 0.f);
    float4 acc2 = make_float4(0.f, 0.f, 0.f, 0.f);
    if (g == 0) acc = *reinterpret_cast<const float4*>(H + (size_t)node * C + c0);  // self-loop
    int e = row[node] + g;
    int end = row[node + 1];
    for (; e + EG < end; e += 2 * EG) {
        int s1 = csr_src[e];
        int s2 = csr_src[e + EG];
        float4 h1 = *reinterpret_cast<const float4*>(H + (size_t)s1 * C + c0);
        float4 h2 = *reinterpret_cast<const float4*>(H + (size_t)s2 * C + c0);
        acc.x += h1.x; acc.y += h1.y; acc.z += h1.z; acc.w += h1.w;
        acc2.x += h2.x; acc2.y += h2.y; acc2.z += h2.z; acc2.w += h2.w;
    }
    if (e < end) {
        int s = csr_src[e];
        float4 hv = *reinterpret_cast<const float4*>(H + (size_t)s * C + c0);
        acc.x += hv.x; acc.y += hv.y; acc.z += hv.z; acc.w += hv.w;
    }
    acc.x += acc2.x; acc.y += acc2.y; acc.z += acc2.z; acc.w += acc2.w;
#pragma unroll
    for (int m = LPN; m < 64; m <<= 1) {
        acc.x += __shfl_xor(acc.x, m);
        acc.y += __shfl_xor(acc.y, m);
        acc.z += __shfl_xor(acc.z, m);
        acc.w += __shfl_xor(acc.w, m);
    }
    if (g == 0) {
        float dv = dinv[node];
        float4 o;
        o.x = acc.x * dv; o.y = acc.y * dv; o.z = acc.z * dv; o.w = acc.w * dv;
        if (HAS_BIAS) {
            o.x += bias[c0 + 0]; o.y += bias[c0 + 1];
            o.z += bias[c0 + 2]; o.w += bias[c0 + 3];
        }
        if (RELU) {
            o.x = fmaxf(o.x, 0.f); o.y = fmaxf(o.y, 0.f);
            o.z = fmaxf(o.z, 0.f); o.w = fmaxf(o.w, 0.f);
        }
        if (POST_SCALE) { o.x *= dv; o.y *= dv; o.z *= dv; o.w *= dv; }
        *reinterpret_cast<float4*>(Y + (size_t)node * C + c0) = o;
    }
}

// ---------------- host launch ----------------

static inline int cdiv(int a, int b) { return (a + b - 1) / b; }

extern "C" void kernel_launch(void* const* d_in, const int* in_sizes, int n_in,
                              void* d_out, int out_size, void* d_ws, size_t ws_size,
                              hipStream_t stream) {
    const float* x   = (const float*)d_in[0];
    const int*   ei  = (const int*)d_in[1];
    const float* We1 = (const float*)d_in[2];
    const float* be1 = (const float*)d_in[3];
    const float* We2 = (const float*)d_in[4];
    const float* be2 = (const float*)d_in[5];
    const float* Wd1 = (const float*)d_in[6];
    const float* bd1 = (const float*)d_in[7];
    const float* Wd2 = (const float*)d_in[8];
    const float* bd2 = (const float*)d_in[9];

    const int n = in_sizes[0] / 128;
    const int E = in_sizes[1] / 2;
    const int* src = ei;
    const int* dst = ei + E;
    const int nbkt = cdiv(n, NPB);
    const int nrb = cdiv(n, 64);
    const int nwv = cdiv(n * 64, 256);      // one wave per node

    // carve workspace (256B aligned)
    char* ws = (char*)d_ws;
    auto carve = [&](size_t bytes) -> void* {
        void* p = (void*)ws;
        ws += (bytes + 255) & ~(size_t)255;
        return p;
    };
    int*   bcnt = (int*)carve((size_t)nbkt * 4);
    int*   bbase= (int*)carve((size_t)(nbkt + 1) * 4);
    int*   bcur = (int*)carve((size_t)nbkt * 4);
    int2*  part = (int2*)carve((size_t)E * 8);
    int*   rowp = (int*)carve((size_t)(n + 1) * 4);
    float* dinv = (float*)carve((size_t)n * 4);
    int*   csr  = (int*)carve((size_t)E * 4);
    float* bufA = (float*)carve((size_t)n * 64 * 4);
    float* bufB = (float*)carve((size_t)n * 64 * 4);
    float* bufC = (float*)carve((size_t)n * 32 * 4);

    // ---- graph preprocessing ----
    zero_int_kernel<<<cdiv(nbkt, 256), 256, 0, stream>>>(bcnt, nbkt);
    bucket_count_kernel<<<256, 256, 0, stream>>>(dst, E, nbkt, bcnt);
    bucket_scan_kernel<<<1, 256, 0, stream>>>(bcnt, nbkt, bbase, bcur, rowp, n);
    pair_scatter_kernel<<<cdiv(E, 256), 256, 0, stream>>>(src, dst, E, bcur, part);
    bucket_csr_kernel<<<nbkt, 256, 0, stream>>>(part, bbase, n, rowp, dinv, csr);

    // ---- layer 1: 128 -> 64 (GEMM then aggregate), relu ----
    // H1s = dinv ⊙ (X We1);  B1 = relu(dinv ⊙ agg(H1s) + b)
    gemm_tile_kernel<128, 64, 64, false, false, true>
        <<<dim3(nrb, 1), 256, 0, stream>>>(x, We1, nullptr, dinv, bufA, n);
    aggregate_kernel<64, true, true, false>
        <<<nwv, 256, 0, stream>>>(bufA, rowp, csr, dinv, be1, bufB, n);

    // ---- layer 2: 64 -> 32 (GEMM then aggregate); output pre-scaled for L3 ----
    // H2s = dinv ⊙ (B1 We2);  Zs = dinv ⊙ (dinv ⊙ agg(H2s) + b)
    gemm_tile_kernel<64, 32, 32, false, false, true>
        <<<dim3(nrb, 1), 128, 0, stream>>>(bufB, We2, nullptr, dinv, bufA, n);
    aggregate_kernel<32, false, true, true>
        <<<nwv, 256, 0, stream>>>(bufA, rowp, csr, dinv, be2, bufC, n);

    // ---- layer 3: 32 -> 64 (aggregate FIRST, then GEMM), relu; pre-scaled for L4 ----
    // A3 = dinv ⊙ agg(Zs)  (= S·Z);  Ds = dinv ⊙ relu(A3 Wd1 + b)
    aggregate_kernel<32, false, false, false>
        <<<nwv, 256, 0, stream>>>(bufC, rowp, csr, dinv, nullptr, bufA, n);
    gemm_tile_kernel<32, 64, 64, true, true, true>
        <<<dim3(nrb, 1), 256, 0, stream>>>(bufA, Wd1, bd1, dinv, bufB, n);

    // ---- layer 4: 64 -> 128 (aggregate FIRST, then GEMM) ----
    // A4 = dinv ⊙ agg(Ds)  (= S·D);  out = A4 Wd2 + b
    aggregate_kernel<64, false, false, false>
        <<<nwv, 256, 0, stream>>>(bufB, rowp, csr, dinv, nullptr, bufA, n);
    gemm_tile_kernel<64, 128, 64, true, false, false>
        <<<dim3(nrb, 2), 256, 0, stream>>>(bufA, Wd2, bd2, dinv, (float*)d_out, n);
}

// Round 6
// 215.607 us; speedup vs baseline: 1.7831x; 1.7831x over previous
//
#include <hip/hip_runtime.h>

// ---------------- graph preprocessing (bucketed counting sort) ----------------
// Buckets of 64 consecutive dst nodes. Exact CSR built with block-local writes.

static constexpr int NPB_SHIFT = 6;           // 64 nodes per bucket
static constexpr int NPB = 1 << NPB_SHIFT;
static constexpr int MAX_BKT = 1024;          // supports n <= 65536
static constexpr int PS_CHUNK = 8192;         // edges per block in blocksort

__global__ __launch_bounds__(256) void zero_int_kernel(int* __restrict__ p, int n) {
    int i = blockIdx.x * blockDim.x + threadIdx.x;
    if (i < n) p[i] = 0;
}

// K2: per-block LDS-binned bucket counts -> global bcnt
__global__ __launch_bounds__(256) void bucket_count_kernel(const int* __restrict__ dst, int E,
                                                           int nbkt, int* __restrict__ bcnt) {
    __shared__ int lc[MAX_BKT];
    int tid = threadIdx.x;
    for (int i = tid; i < nbkt; i += 256) lc[i] = 0;
    __syncthreads();
    for (int e = blockIdx.x * 256 + tid; e < E; e += gridDim.x * 256)
        atomicAdd(&lc[dst[e] >> NPB_SHIFT], 1);
    __syncthreads();
    for (int i = tid; i < nbkt; i += 256)
        if (lc[i]) atomicAdd(&bcnt[i], lc[i]);
}

// K3: single-block exclusive scan of bcnt -> bbase[0..nbkt], bcur; rowp[n] = E
__global__ __launch_bounds__(256) void bucket_scan_kernel(const int* __restrict__ bcnt, int nbkt,
                                                          int* __restrict__ bbase,
                                                          int* __restrict__ bcur,
                                                          int* __restrict__ rowp, int n) {
    __shared__ int wsum[4];
    int tid = threadIdx.x, lane = tid & 63, w = tid >> 6;
    int chunk = (nbkt + 255) / 256;
    int begin = tid * chunk;
    int end = begin + chunk; if (end > nbkt) end = nbkt;
    int s = 0;
    for (int i = begin; i < end; ++i) s += bcnt[i];
    int inc = s;
#pragma unroll
    for (int m = 1; m < 64; m <<= 1) {
        int u = __shfl_up(inc, m);
        if (lane >= m) inc += u;
    }
    if (lane == 63) wsum[w] = inc;
    __syncthreads();
    int off = 0;
    for (int i = 0; i < w; ++i) off += wsum[i];
    int run = off + inc - s;
    for (int i = begin; i < end; ++i) {
        bbase[i] = run; bcur[i] = run;
        run += bcnt[i];
    }
    if (tid == 255) { bbase[nbkt] = run; rowp[n] = run; }   // run == E
}

// K4: block-local LDS bucket sort, then bulk-reserve + coalesced write-out.
// One global atomic per (block, non-empty bucket) instead of per edge.
__global__ __launch_bounds__(256) void pair_blocksort_kernel(const int* __restrict__ src,
                                                             const int* __restrict__ dst,
                                                             int E, int nbkt,
                                                             int* __restrict__ bcur,
                                                             int2* __restrict__ part) {
    __shared__ int2 pairs[PS_CHUNK];          // 64 KB
    __shared__ int lcnt[MAX_BKT];             // counts, later reused as gpos
    __shared__ int lbase[MAX_BKT];
    __shared__ int lcur[MAX_BKT];
    __shared__ int wsum[4];
    const int tid = threadIdx.x;
    const int e0 = blockIdx.x * PS_CHUNK;
    int e1 = e0 + PS_CHUNK; if (e1 > E) e1 = E;

    for (int i = tid; i < nbkt; i += 256) lcnt[i] = 0;
    __syncthreads();
    // pass 1: count
    for (int i = e0 + tid; i < e1; i += 256)
        atomicAdd(&lcnt[dst[i] >> NPB_SHIFT], 1);
    __syncthreads();
    // scan 782 counters: 256 threads x 4 buckets
    {
        int b0 = tid * 4;
        int v[4]; int s = 0;
#pragma unroll
        for (int k = 0; k < 4; ++k) {
            int b = b0 + k;
            v[k] = (b < nbkt) ? lcnt[b] : 0;
            s += v[k];
        }
        int lane = tid & 63, w = tid >> 6;
        int inc = s;
#pragma unroll
        for (int m = 1; m < 64; m <<= 1) {
            int u = __shfl_up(inc, m);
            if (lane >= m) inc += u;
        }
        if (lane == 63) wsum[w] = inc;
        __syncthreads();
        int off = 0;
        for (int i = 0; i < w; ++i) off += wsum[i];
        int run = off + inc - s;
#pragma unroll
        for (int k = 0; k < 4; ++k) {
            int b = b0 + k;
            if (b < nbkt) { lbase[b] = run; lcur[b] = run; }
            run += v[k];
        }
    }
    __syncthreads();
    // pass 2: scatter into bucket-sorted LDS order (src/dst re-read, L2-hot)
    for (int i = e0 + tid; i < e1; i += 256) {
        int s = src[i], d = dst[i];
        int p = atomicAdd(&lcur[d >> NPB_SHIFT], 1);
        pairs[p] = make_int2(s, d);
    }
    __syncthreads();
    // reserve global space: one atomic per non-empty bucket
    for (int b = tid; b < nbkt; b += 256) {
        int c = lcur[b] - lbase[b];
        lcnt[b] = c ? atomicAdd(&bcur[b], c) : 0;        // lcnt becomes gpos
    }
    __syncthreads();
    // write out: consecutive LDS slots in a bucket -> consecutive global slots
    const int cnt = e1 - e0;
    for (int i = tid; i < cnt; i += 256) {
        int2 pr = pairs[i];
        int b = pr.y >> NPB_SHIFT;
        part[lcnt[b] + (i - lbase[b])] = pr;
    }
}

// K5: one block per bucket: per-node counts (LDS), wave scan -> rowp/dinv,
// then localized scatter of csr within the block-exclusive region.
__global__ __launch_bounds__(256) void bucket_csr_kernel(const int2* __restrict__ part,
                                                         const int* __restrict__ bbase, int n,
                                                         int* __restrict__ rowp,
                                                         float* __restrict__ dinv,
                                                         int* __restrict__ csr) {
    __shared__ int lcnt[NPB];
    int b = blockIdx.x, tid = threadIdx.x;
    int node0 = b << NPB_SHIFT;
    int nloc = n - node0; if (nloc > NPB) nloc = NPB;
    int p0 = bbase[b], p1 = bbase[b + 1];
    if (tid < NPB) lcnt[tid] = 0;
    __syncthreads();
    for (int i = p0 + tid; i < p1; i += 256)
        atomicAdd(&lcnt[part[i].y & (NPB - 1)], 1);
    __syncthreads();
    if (tid < 64) {                       // wave 0: scan 64 counters
        int c = lcnt[tid];
        int inc = c;
#pragma unroll
        for (int m = 1; m < 64; m <<= 1) {
            int u = __shfl_up(inc, m);
            if (tid >= m) inc += u;
        }
        int base = p0 + inc - c;
        if (tid < nloc) {
            rowp[node0 + tid] = base;
            dinv[node0 + tid] = rsqrtf((float)(c + 1));    // +1 self-loop
        }
        lcnt[tid] = base;                 // becomes the scatter cursor
    }
    __syncthreads();
    for (int i = p0 + tid; i < p1; i += 256) {
        int2 pr = part[i];
        int pos = atomicAdd(&lcnt[pr.y & (NPB - 1)], 1);
        csr[pos] = pr.x;
    }
}

// ---------------- per-layer kernels ----------------

// Block-tiled GEMM: H[r][c] = epi(sum_k X[r][k] W[k][c])
// epi: +bias (BIAS), relu (RELU), * dinv[r] (SCALE) — in that order.
template <int K, int OUT, int BN, bool BIAS, bool RELU, bool SCALE>
__global__ __launch_bounds__(16 * (BN / 4)) void gemm_tile_kernel(
        const float* __restrict__ X, const float* __restrict__ W,
        const float* __restrict__ bias, const float* __restrict__ dinv,
        float* __restrict__ H, int n) {
    constexpr int BM = 64;
    constexpr int KB = (K > 64) ? 64 : K;
    constexpr int NTHR = 16 * (BN / 4);
    constexpr int KV = KB / 4;              // float4s per A row chunk

    __shared__ float At[KB][BM + 4];        // [k][r], stride 68 floats
    __shared__ float Bl[K][BN];

    const int tid = threadIdx.x;
    const int tx = tid % (BN / 4);
    const int ty = tid / (BN / 4);
    const int rb = blockIdx.x * BM;
    const int co = blockIdx.y * BN;

    // load B panel (W[:, co:co+BN]) once
    for (int i = tid; i < K * BN / 4; i += NTHR) {
        int k = i / (BN / 4);
        int c0 = (i % (BN / 4)) * 4;
        *reinterpret_cast<float4*>(&Bl[k][c0]) =
            *reinterpret_cast<const float4*>(&W[(size_t)k * OUT + co + c0]);
    }

    float acc[4][4] = {};

#pragma unroll
    for (int ch = 0; ch < K / KB; ++ch) {
        if (ch) __syncthreads();            // previous chunk's readers done
        // stage A chunk transposed
        for (int i = tid; i < BM * KV; i += NTHR) {
            int r = i / KV;
            int k0 = (i % KV) * 4;
            int rg = rb + r; if (rg > n - 1) rg = n - 1;     // clamp tail
            float4 xv = *reinterpret_cast<const float4*>(&X[(size_t)rg * K + ch * KB + k0]);
            At[k0 + 0][r] = xv.x;
            At[k0 + 1][r] = xv.y;
            At[k0 + 2][r] = xv.z;
            At[k0 + 3][r] = xv.w;
        }
        __syncthreads();

#pragma unroll 8
        for (int k = 0; k < KB; ++k) {
            float4 a = *reinterpret_cast<const float4*>(&At[k][ty * 4]);
            float4 b = *reinterpret_cast<const float4*>(&Bl[ch * KB + k][tx * 4]);
            acc[0][0] = fmaf(a.x, b.x, acc[0][0]); acc[0][1] = fmaf(a.x, b.y, acc[0][1]);
            acc[0][2] = fmaf(a.x, b.z, acc[0][2]); acc[0][3] = fmaf(a.x, b.w, acc[0][3]);
            acc[1][0] = fmaf(a.y, b.x, acc[1][0]); acc[1][1] = fmaf(a.y, b.y, acc[1][1]);
            acc[1][2] = fmaf(a.y, b.z, acc[1][2]); acc[1][3] = fmaf(a.y, b.w, acc[1][3]);
            acc[2][0] = fmaf(a.z, b.x, acc[2][0]); acc[2][1] = fmaf(a.z, b.y, acc[2][1]);
            acc[2][2] = fmaf(a.z, b.z, acc[2][2]); acc[2][3] = fmaf(a.z, b.w, acc[2][3]);
            acc[3][0] = fmaf(a.w, b.x, acc[3][0]); acc[3][1] = fmaf(a.w, b.y, acc[3][1]);
            acc[3][2] = fmaf(a.w, b.z, acc[3][2]); acc[3][3] = fmaf(a.w, b.w, acc[3][3]);
        }
    }

    float4 bv = make_float4(0.f, 0.f, 0.f, 0.f);
    if (BIAS) bv = *reinterpret_cast<const float4*>(&bias[co + tx * 4]);
    int r0 = rb + ty * 4;
#pragma unroll
    for (int i = 0; i < 4; ++i) {
        int r = r0 + i;
        if (r < n) {
            float4 o;
            o.x = acc[i][0]; o.y = acc[i][1]; o.z = acc[i][2]; o.w = acc[i][3];
            if (BIAS) { o.x += bv.x; o.y += bv.y; o.z += bv.z; o.w += bv.w; }
            if (RELU) {
                o.x = fmaxf(o.x, 0.f); o.y = fmaxf(o.y, 0.f);
                o.z = fmaxf(o.z, 0.f); o.w = fmaxf(o.w, 0.f);
            }
            if (SCALE) {
                float dv = dinv[r];
                o.x *= dv; o.y *= dv; o.z *= dv; o.w *= dv;
            }
            *reinterpret_cast<float4*>(&H[(size_t)r * OUT + co + tx * 4]) = o;
        }
    }
}

// One wave per node. Lanes split into EG = 64/(C/4) edge groups; each lane loads
// float4 of channels; 2x-unrolled edge loop for MLP. Cross-group shfl_xor reduce.
// o = dinv[d]*(H[d]+sum H[s]); if BIAS o += b; if RELU relu; if POST o *= dinv[d].
template <int C, bool RELU, bool HAS_BIAS, bool POST_SCALE>
__global__ __launch_bounds__(256) void aggregate_kernel(const float* __restrict__ H,
                                                        const int* __restrict__ row,
                                                        const int* __restrict__ csr_src,
                                                        const float* __restrict__ dinv,
                                                        const float* __restrict__ bias,
                                                        float* __restrict__ Y, int n) {
    constexpr int LPN = C / 4;        // lanes covering one row: 8 / 16
    constexpr int EG = 64 / LPN;      // edge groups: 8 / 4
    int wid = (blockIdx.x * blockDim.x + threadIdx.x) >> 6;
    if (wid >= n) return;             // wave-uniform exit
    int lane = threadIdx.x & 63;
    int g = lane / LPN;
    int c0 = (lane % LPN) * 4;
    const int node = wid;

    float4 acc = make_float4(0.f, 0.f, 0.f, 0.f);
    float4 acc2 = make_float4(0.f, 0.f, 0.f, 0.f);
    if (g == 0) acc = *reinterpret_cast<const float4*>(H + (size_t)node * C + c0);  // self-loop
    int e = row[node] + g;
    int end = row[node + 1];
    for (; e + EG < end; e += 2 * EG) {
        int s1 = csr_src[e];
        int s2 = csr_src[e + EG];
        float4 h1 = *reinterpret_cast<const float4*>(H + (size_t)s1 * C + c0);
        float4 h2 = *reinterpret_cast<const float4*>(H + (size_t)s2 * C + c0);
        acc.x += h1.x; acc.y += h1.y; acc.z += h1.z; acc.w += h1.w;
        acc2.x += h2.x; acc2.y += h2.y; acc2.z += h2.z; acc2.w += h2.w;
    }
    if (e < end) {
        int s = csr_src[e];
        float4 hv = *reinterpret_cast<const float4*>(H + (size_t)s * C + c0);
        acc.x += hv.x; acc.y += hv.y; acc.z += hv.z; acc.w += hv.w;
    }
    acc.x += acc2.x; acc.y += acc2.y; acc.z += acc2.z; acc.w += acc2.w;
#pragma unroll
    for (int m = LPN; m < 64; m <<= 1) {
        acc.x += __shfl_xor(acc.x, m);
        acc.y += __shfl_xor(acc.y, m);
        acc.z += __shfl_xor(acc.z, m);
        acc.w += __shfl_xor(acc.w, m);
    }
    if (g == 0) {
        float dv = dinv[node];
        float4 o;
        o.x = acc.x * dv; o.y = acc.y * dv; o.z = acc.z * dv; o.w = acc.w * dv;
        if (HAS_BIAS) {
            o.x += bias[c0 + 0]; o.y += bias[c0 + 1];
            o.z += bias[c0 + 2]; o.w += bias[c0 + 3];
        }
        if (RELU) {
            o.x = fmaxf(o.x, 0.f); o.y = fmaxf(o.y, 0.f);
            o.z = fmaxf(o.z, 0.f); o.w = fmaxf(o.w, 0.f);
        }
        if (POST_SCALE) { o.x *= dv; o.y *= dv; o.z *= dv; o.w *= dv; }
        *reinterpret_cast<float4*>(Y + (size_t)node * C + c0) = o;
    }
}

// ---------------- host launch ----------------

static inline int cdiv(int a, int b) { return (a + b - 1) / b; }

extern "C" void kernel_launch(void* const* d_in, const int* in_sizes, int n_in,
                              void* d_out, int out_size, void* d_ws, size_t ws_size,
                              hipStream_t stream) {
    const float* x   = (const float*)d_in[0];
    const int*   ei  = (const int*)d_in[1];
    const float* We1 = (const float*)d_in[2];
    const float* be1 = (const float*)d_in[3];
    const float* We2 = (const float*)d_in[4];
    const float* be2 = (const float*)d_in[5];
    const float* Wd1 = (const float*)d_in[6];
    const float* bd1 = (const float*)d_in[7];
    const float* Wd2 = (const float*)d_in[8];
    const float* bd2 = (const float*)d_in[9];

    const int n = in_sizes[0] / 128;
    const int E = in_sizes[1] / 2;
    const int* src = ei;
    const int* dst = ei + E;
    const int nbkt = cdiv(n, NPB);
    const int nrb = cdiv(n, 64);
    const int nwv = cdiv(n * 64, 256);      // one wave per node

    // carve workspace (256B aligned)
    char* ws = (char*)d_ws;
    auto carve = [&](size_t bytes) -> void* {
        void* p = (void*)ws;
        ws += (bytes + 255) & ~(size_t)255;
        return p;
    };
    int*   bcnt = (int*)carve((size_t)nbkt * 4);
    int*   bbase= (int*)carve((size_t)(nbkt + 1) * 4);
    int*   bcur = (int*)carve((size_t)nbkt * 4);
    int2*  part = (int2*)carve((size_t)E * 8);
    int*   rowp = (int*)carve((size_t)(n + 1) * 4);
    float* dinv = (float*)carve((size_t)n * 4);
    int*   csr  = (int*)carve((size_t)E * 4);
    float* bufA = (float*)carve((size_t)n * 64 * 4);
    float* bufB = (float*)carve((size_t)n * 64 * 4);
    float* bufC = (float*)carve((size_t)n * 32 * 4);

    // ---- graph preprocessing ----
    zero_int_kernel<<<cdiv(nbkt, 256), 256, 0, stream>>>(bcnt, nbkt);
    bucket_count_kernel<<<256, 256, 0, stream>>>(dst, E, nbkt, bcnt);
    bucket_scan_kernel<<<1, 256, 0, stream>>>(bcnt, nbkt, bbase, bcur, rowp, n);
    pair_blocksort_kernel<<<cdiv(E, PS_CHUNK), 256, 0, stream>>>(src, dst, E, nbkt, bcur, part);
    bucket_csr_kernel<<<nbkt, 256, 0, stream>>>(part, bbase, n, rowp, dinv, csr);

    // ---- layer 1: 128 -> 64 (GEMM then aggregate), relu ----
    // H1s = dinv ⊙ (X We1);  B1 = relu(dinv ⊙ agg(H1s) + b)
    gemm_tile_kernel<128, 64, 64, false, false, true>
        <<<dim3(nrb, 1), 256, 0, stream>>>(x, We1, nullptr, dinv, bufA, n);
    aggregate_kernel<64, true, true, false>
        <<<nwv, 256, 0, stream>>>(bufA, rowp, csr, dinv, be1, bufB, n);

    // ---- layer 2: 64 -> 32 (GEMM then aggregate); output pre-scaled for L3 ----
    // H2s = dinv ⊙ (B1 We2);  Zs = dinv ⊙ (dinv ⊙ agg(H2s) + b)
    gemm_tile_kernel<64, 32, 32, false, false, true>
        <<<dim3(nrb, 1), 128, 0, stream>>>(bufB, We2, nullptr, dinv, bufA, n);
    aggregate_kernel<32, false, true, true>
        <<<nwv, 256, 0, stream>>>(bufA, rowp, csr, dinv, be2, bufC, n);

    // ---- layer 3: 32 -> 64 (aggregate FIRST, then GEMM), relu; pre-scaled for L4 ----
    // A3 = dinv ⊙ agg(Zs)  (= S·Z);  Ds = dinv ⊙ relu(A3 Wd1 + b)
    aggregate_kernel<32, false, false, false>
        <<<nwv, 256, 0, stream>>>(bufC, rowp, csr, dinv, nullptr, bufA, n);
    gemm_tile_kernel<32, 64, 64, true, true, true>
        <<<dim3(nrb, 1), 256, 0, stream>>>(bufA, Wd1, bd1, dinv, bufB, n);

    // ---- layer 4: 64 -> 128 (aggregate FIRST, then GEMM) ----
    // A4 = dinv ⊙ agg(Ds)  (= S·D);  out = A4 Wd2 + b
    aggregate_kernel<64, false, false, false>
        <<<nwv, 256, 0, stream>>>(bufB, rowp, csr, dinv, nullptr, bufA, n);
    gemm_tile_kernel<64, 128, 64, true, false, false>
        <<<dim3(nrb, 2), 256, 0, stream>>>(bufA, Wd2, bd2, dinv, (float*)d_out, n);
}

// Round 7
// 215.324 us; speedup vs baseline: 1.7855x; 1.0013x over previous
//
#include <hip/hip_runtime.h>

typedef _Float16 half4 __attribute__((ext_vector_type(4)));

// ---------------- graph preprocessing (bucketed counting sort) ----------------
// Buckets of 64 consecutive dst nodes. Exact CSR built with block-local writes.

static constexpr int NPB_SHIFT = 6;           // 64 nodes per bucket
static constexpr int NPB = 1 << NPB_SHIFT;
static constexpr int MAX_BKT = 1024;          // supports n <= 65536
static constexpr int PS_CHUNK = 8192;         // edges per block in blocksort

__global__ __launch_bounds__(256) void zero_int_kernel(int* __restrict__ p, int n) {
    int i = blockIdx.x * blockDim.x + threadIdx.x;
    if (i < n) p[i] = 0;
}

// K2: per-block LDS-binned bucket counts -> global bcnt
__global__ __launch_bounds__(256) void bucket_count_kernel(const int* __restrict__ dst, int E,
                                                           int nbkt, int* __restrict__ bcnt) {
    __shared__ int lc[MAX_BKT];
    int tid = threadIdx.x;
    for (int i = tid; i < nbkt; i += 256) lc[i] = 0;
    __syncthreads();
    for (int e = blockIdx.x * 256 + tid; e < E; e += gridDim.x * 256)
        atomicAdd(&lc[dst[e] >> NPB_SHIFT], 1);
    __syncthreads();
    for (int i = tid; i < nbkt; i += 256)
        if (lc[i]) atomicAdd(&bcnt[i], lc[i]);
}

// K3: single-block exclusive scan of bcnt -> bbase[0..nbkt], bcur; rowp[n] = E
__global__ __launch_bounds__(256) void bucket_scan_kernel(const int* __restrict__ bcnt, int nbkt,
                                                          int* __restrict__ bbase,
                                                          int* __restrict__ bcur,
                                                          int* __restrict__ rowp, int n) {
    __shared__ int wsum[4];
    int tid = threadIdx.x, lane = tid & 63, w = tid >> 6;
    int chunk = (nbkt + 255) / 256;
    int begin = tid * chunk;
    int end = begin + chunk; if (end > nbkt) end = nbkt;
    int s = 0;
    for (int i = begin; i < end; ++i) s += bcnt[i];
    int inc = s;
#pragma unroll
    for (int m = 1; m < 64; m <<= 1) {
        int u = __shfl_up(inc, m);
        if (lane >= m) inc += u;
    }
    if (lane == 63) wsum[w] = inc;
    __syncthreads();
    int off = 0;
    for (int i = 0; i < w; ++i) off += wsum[i];
    int run = off + inc - s;
    for (int i = begin; i < end; ++i) {
        bbase[i] = run; bcur[i] = run;
        run += bcnt[i];
    }
    if (tid == 255) { bbase[nbkt] = run; rowp[n] = run; }   // run == E
}

// K4: block-local LDS bucket sort, then bulk-reserve + coalesced write-out.
// One global atomic per (block, non-empty bucket) instead of per edge.
__global__ __launch_bounds__(256) void pair_blocksort_kernel(const int* __restrict__ src,
                                                             const int* __restrict__ dst,
                                                             int E, int nbkt,
                                                             int* __restrict__ bcur,
                                                             int2* __restrict__ part) {
    __shared__ int2 pairs[PS_CHUNK];          // 64 KB
    __shared__ int lcnt[MAX_BKT];             // counts, later reused as gpos
    __shared__ int lbase[MAX_BKT];
    __shared__ int lcur[MAX_BKT];
    __shared__ int wsum[4];
    const int tid = threadIdx.x;
    const int e0 = blockIdx.x * PS_CHUNK;
    int e1 = e0 + PS_CHUNK; if (e1 > E) e1 = E;

    for (int i = tid; i < nbkt; i += 256) lcnt[i] = 0;
    __syncthreads();
    // pass 1: count
    for (int i = e0 + tid; i < e1; i += 256)
        atomicAdd(&lcnt[dst[i] >> NPB_SHIFT], 1);
    __syncthreads();
    // scan counters: 256 threads x 4 buckets
    {
        int b0 = tid * 4;
        int v[4]; int s = 0;
#pragma unroll
        for (int k = 0; k < 4; ++k) {
            int b = b0 + k;
            v[k] = (b < nbkt) ? lcnt[b] : 0;
            s += v[k];
        }
        int lane = tid & 63, w = tid >> 6;
        int inc = s;
#pragma unroll
        for (int m = 1; m < 64; m <<= 1) {
            int u = __shfl_up(inc, m);
            if (lane >= m) inc += u;
        }
        if (lane == 63) wsum[w] = inc;
        __syncthreads();
        int off = 0;
        for (int i = 0; i < w; ++i) off += wsum[i];
        int run = off + inc - s;
#pragma unroll
        for (int k = 0; k < 4; ++k) {
            int b = b0 + k;
            if (b < nbkt) { lbase[b] = run; lcur[b] = run; }
            run += v[k];
        }
    }
    __syncthreads();
    // pass 2: scatter into bucket-sorted LDS order (src/dst re-read, L2-hot)
    for (int i = e0 + tid; i < e1; i += 256) {
        int s = src[i], d = dst[i];
        int p = atomicAdd(&lcur[d >> NPB_SHIFT], 1);
        pairs[p] = make_int2(s, d);
    }
    __syncthreads();
    // reserve global space: one atomic per non-empty bucket
    for (int b = tid; b < nbkt; b += 256) {
        int c = lcur[b] - lbase[b];
        lcnt[b] = c ? atomicAdd(&bcur[b], c) : 0;        // lcnt becomes gpos
    }
    __syncthreads();
    // write out: consecutive LDS slots in a bucket -> consecutive global slots
    const int cnt = e1 - e0;
    for (int i = tid; i < cnt; i += 256) {
        int2 pr = pairs[i];
        int b = pr.y >> NPB_SHIFT;
        part[lcnt[b] + (i - lbase[b])] = pr;
    }
}

// K5: one block per bucket: per-node counts (LDS), wave scan -> rowp/dinv,
// then localized scatter of csr within the block-exclusive region.
__global__ __launch_bounds__(256) void bucket_csr_kernel(const int2* __restrict__ part,
                                                         const int* __restrict__ bbase, int n,
                                                         int* __restrict__ rowp,
                                                         float* __restrict__ dinv,
                                                         int* __restrict__ csr) {
    __shared__ int lcnt[NPB];
    int b = blockIdx.x, tid = threadIdx.x;
    int node0 = b << NPB_SHIFT;
    int nloc = n - node0; if (nloc > NPB) nloc = NPB;
    int p0 = bbase[b], p1 = bbase[b + 1];
    if (tid < NPB) lcnt[tid] = 0;
    __syncthreads();
    for (int i = p0 + tid; i < p1; i += 256)
        atomicAdd(&lcnt[part[i].y & (NPB - 1)], 1);
    __syncthreads();
    if (tid < 64) {                       // wave 0: scan 64 counters
        int c = lcnt[tid];
        int inc = c;
#pragma unroll
        for (int m = 1; m < 64; m <<= 1) {
            int u = __shfl_up(inc, m);
            if (tid >= m) inc += u;
        }
        int base = p0 + inc - c;
        if (tid < nloc) {
            rowp[node0 + tid] = base;
            dinv[node0 + tid] = rsqrtf((float)(c + 1));    // +1 self-loop
        }
        lcnt[tid] = base;                 // becomes the scatter cursor
    }
    __syncthreads();
    for (int i = p0 + tid; i < p1; i += 256) {
        int2 pr = part[i];
        int pos = atomicAdd(&lcnt[pr.y & (NPB - 1)], 1);
        csr[pos] = pr.x;
    }
}

// ---------------- per-layer kernels ----------------

template <bool HALF>
__device__ __forceinline__ float4 ldrow4(const void* H, size_t off) {
    if constexpr (HALF) {
        half4 h = *reinterpret_cast<const half4*>(reinterpret_cast<const _Float16*>(H) + off);
        return make_float4((float)h.x, (float)h.y, (float)h.z, (float)h.w);
    } else {
        return *reinterpret_cast<const float4*>(reinterpret_cast<const float*>(H) + off);
    }
}

// Block-tiled GEMM: H[r][c] = epi(sum_k X[r][k] W[k][c])
// epi: +bias (BIAS), relu (RELU), * dinv[r] (SCALE); output fp32 or fp16 (HALF_OUT).
template <int K, int OUT, int BN, bool BIAS, bool RELU, bool SCALE, bool HALF_OUT>
__global__ __launch_bounds__(16 * (BN / 4)) void gemm_tile_kernel(
        const float* __restrict__ X, const float* __restrict__ W,
        const float* __restrict__ bias, const float* __restrict__ dinv,
        void* __restrict__ Hout, int n) {
    constexpr int BM = 64;
    constexpr int KB = (K > 64) ? 64 : K;
    constexpr int NTHR = 16 * (BN / 4);
    constexpr int KV = KB / 4;              // float4s per A row chunk

    __shared__ float At[KB][BM + 4];        // [k][r], stride 68 floats
    __shared__ float Bl[K][BN];

    const int tid = threadIdx.x;
    const int tx = tid % (BN / 4);
    const int ty = tid / (BN / 4);
    const int rb = blockIdx.x * BM;
    const int co = blockIdx.y * BN;

    // load B panel (W[:, co:co+BN]) once
    for (int i = tid; i < K * BN / 4; i += NTHR) {
        int k = i / (BN / 4);
        int c0 = (i % (BN / 4)) * 4;
        *reinterpret_cast<float4*>(&Bl[k][c0]) =
            *reinterpret_cast<const float4*>(&W[(size_t)k * OUT + co + c0]);
    }

    float acc[4][4] = {};

#pragma unroll
    for (int ch = 0; ch < K / KB; ++ch) {
        if (ch) __syncthreads();            // previous chunk's readers done
        // stage A chunk transposed
        for (int i = tid; i < BM * KV; i += NTHR) {
            int r = i / KV;
            int k0 = (i % KV) * 4;
            int rg = rb + r; if (rg > n - 1) rg = n - 1;     // clamp tail
            float4 xv = *reinterpret_cast<const float4*>(&X[(size_t)rg * K + ch * KB + k0]);
            At[k0 + 0][r] = xv.x;
            At[k0 + 1][r] = xv.y;
            At[k0 + 2][r] = xv.z;
            At[k0 + 3][r] = xv.w;
        }
        __syncthreads();

#pragma unroll 8
        for (int k = 0; k < KB; ++k) {
            float4 a = *reinterpret_cast<const float4*>(&At[k][ty * 4]);
            float4 b = *reinterpret_cast<const float4*>(&Bl[ch * KB + k][tx * 4]);
            acc[0][0] = fmaf(a.x, b.x, acc[0][0]); acc[0][1] = fmaf(a.x, b.y, acc[0][1]);
            acc[0][2] = fmaf(a.x, b.z, acc[0][2]); acc[0][3] = fmaf(a.x, b.w, acc[0][3]);
            acc[1][0] = fmaf(a.y, b.x, acc[1][0]); acc[1][1] = fmaf(a.y, b.y, acc[1][1]);
            acc[1][2] = fmaf(a.y, b.z, acc[1][2]); acc[1][3] = fmaf(a.y, b.w, acc[1][3]);
            acc[2][0] = fmaf(a.z, b.x, acc[2][0]); acc[2][1] = fmaf(a.z, b.y, acc[2][1]);
            acc[2][2] = fmaf(a.z, b.z, acc[2][2]); acc[2][3] = fmaf(a.z, b.w, acc[2][3]);
            acc[3][0] = fmaf(a.w, b.x, acc[3][0]); acc[3][1] = fmaf(a.w, b.y, acc[3][1]);
            acc[3][2] = fmaf(a.w, b.z, acc[3][2]); acc[3][3] = fmaf(a.w, b.w, acc[3][3]);
        }
    }

    float4 bv = make_float4(0.f, 0.f, 0.f, 0.f);
    if (BIAS) bv = *reinterpret_cast<const float4*>(&bias[co + tx * 4]);
    int r0 = rb + ty * 4;
#pragma unroll
    for (int i = 0; i < 4; ++i) {
        int r = r0 + i;
        if (r < n) {
            float4 o;
            o.x = acc[i][0]; o.y = acc[i][1]; o.z = acc[i][2]; o.w = acc[i][3];
            if (BIAS) { o.x += bv.x; o.y += bv.y; o.z += bv.z; o.w += bv.w; }
            if (RELU) {
                o.x = fmaxf(o.x, 0.f); o.y = fmaxf(o.y, 0.f);
                o.z = fmaxf(o.z, 0.f); o.w = fmaxf(o.w, 0.f);
            }
            if (SCALE) {
                float dv = dinv[r];
                o.x *= dv; o.y *= dv; o.z *= dv; o.w *= dv;
            }
            if (HALF_OUT) {
                half4 hv;
                hv.x = (_Float16)o.x; hv.y = (_Float16)o.y;
                hv.z = (_Float16)o.z; hv.w = (_Float16)o.w;
                *reinterpret_cast<half4*>(reinterpret_cast<_Float16*>(Hout) +
                                          (size_t)r * OUT + co + tx * 4) = hv;
            } else {
                *reinterpret_cast<float4*>(reinterpret_cast<float*>(Hout) +
                                           (size_t)r * OUT + co + tx * 4) = o;
            }
        }
    }
}

// One wave per node. Lanes split into EG = 64/(C/4) edge groups; each lane covers
// 4 channels; 4-deep unrolled gather pipeline. Cross-group shfl_xor reduce.
// o = dinv[d]*(H[d]+sum H[s]); if BIAS o += b; if RELU relu; if POST o *= dinv[d].
template <int C, bool RELU, bool HAS_BIAS, bool POST_SCALE, bool HALF_IN>
__global__ __launch_bounds__(256) void aggregate_kernel(const void* __restrict__ H,
                                                        const int* __restrict__ row,
                                                        const int* __restrict__ csr_src,
                                                        const float* __restrict__ dinv,
                                                        const float* __restrict__ bias,
                                                        float* __restrict__ Y, int n) {
    constexpr int LPN = C / 4;        // lanes covering one row: 8 / 16
    constexpr int EG = 64 / LPN;      // edge groups: 8 / 4
    int wid = (blockIdx.x * blockDim.x + threadIdx.x) >> 6;
    if (wid >= n) return;             // wave-uniform exit
    int lane = threadIdx.x & 63;
    int g = lane / LPN;
    int c0 = (lane % LPN) * 4;
    const int node = wid;

    float4 a0 = make_float4(0.f, 0.f, 0.f, 0.f);
    float4 a1 = a0, a2 = a0, a3 = a0;
    if (g == 0) a0 = ldrow4<HALF_IN>(H, (size_t)node * C + c0);   // self-loop
    int e = row[node] + g;
    int end = row[node + 1];
    for (; e + 3 * EG < end; e += 4 * EG) {
        int s0 = csr_src[e];
        int s1 = csr_src[e + EG];
        int s2 = csr_src[e + 2 * EG];
        int s3 = csr_src[e + 3 * EG];
        float4 h0 = ldrow4<HALF_IN>(H, (size_t)s0 * C + c0);
        float4 h1 = ldrow4<HALF_IN>(H, (size_t)s1 * C + c0);
        float4 h2 = ldrow4<HALF_IN>(H, (size_t)s2 * C + c0);
        float4 h3 = ldrow4<HALF_IN>(H, (size_t)s3 * C + c0);
        a0.x += h0.x; a0.y += h0.y; a0.z += h0.z; a0.w += h0.w;
        a1.x += h1.x; a1.y += h1.y; a1.z += h1.z; a1.w += h1.w;
        a2.x += h2.x; a2.y += h2.y; a2.z += h2.z; a2.w += h2.w;
        a3.x += h3.x; a3.y += h3.y; a3.z += h3.z; a3.w += h3.w;
    }
    for (; e < end; e += EG) {
        int s = csr_src[e];
        float4 hv = ldrow4<HALF_IN>(H, (size_t)s * C + c0);
        a0.x += hv.x; a0.y += hv.y; a0.z += hv.z; a0.w += hv.w;
    }
    float4 acc;
    acc.x = (a0.x + a1.x) + (a2.x + a3.x);
    acc.y = (a0.y + a1.y) + (a2.y + a3.y);
    acc.z = (a0.z + a1.z) + (a2.z + a3.z);
    acc.w = (a0.w + a1.w) + (a2.w + a3.w);
#pragma unroll
    for (int m = LPN; m < 64; m <<= 1) {
        acc.x += __shfl_xor(acc.x, m);
        acc.y += __shfl_xor(acc.y, m);
        acc.z += __shfl_xor(acc.z, m);
        acc.w += __shfl_xor(acc.w, m);
    }
    if (g == 0) {
        float dv = dinv[node];
        float4 o;
        o.x = acc.x * dv; o.y = acc.y * dv; o.z = acc.z * dv; o.w = acc.w * dv;
        if (HAS_BIAS) {
            o.x += bias[c0 + 0]; o.y += bias[c0 + 1];
            o.z += bias[c0 + 2]; o.w += bias[c0 + 3];
        }
        if (RELU) {
            o.x = fmaxf(o.x, 0.f); o.y = fmaxf(o.y, 0.f);
            o.z = fmaxf(o.z, 0.f); o.w = fmaxf(o.w, 0.f);
        }
        if (POST_SCALE) { o.x *= dv; o.y *= dv; o.z *= dv; o.w *= dv; }
        *reinterpret_cast<float4*>(Y + (size_t)node * C + c0) = o;
    }
}

// ---------------- host launch ----------------

static inline int cdiv(int a, int b) { return (a + b - 1) / b; }

extern "C" void kernel_launch(void* const* d_in, const int* in_sizes, int n_in,
                              void* d_out, int out_size, void* d_ws, size_t ws_size,
                              hipStream_t stream) {
    const float* x   = (const float*)d_in[0];
    const int*   ei  = (const int*)d_in[1];
    const float* We1 = (const float*)d_in[2];
    const float* be1 = (const float*)d_in[3];
    const float* We2 = (const float*)d_in[4];
    const float* be2 = (const float*)d_in[5];
    const float* Wd1 = (const float*)d_in[6];
    const float* bd1 = (const float*)d_in[7];
    const float* Wd2 = (const float*)d_in[8];
    const float* bd2 = (const float*)d_in[9];

    const int n = in_sizes[0] / 128;
    const int E = in_sizes[1] / 2;
    const int* src = ei;
    const int* dst = ei + E;
    const int nbkt = cdiv(n, NPB);
    const int nrb = cdiv(n, 64);
    const int nwv = cdiv(n * 64, 256);      // one wave per node

    // carve workspace (256B aligned)
    char* ws = (char*)d_ws;
    auto carve = [&](size_t bytes) -> void* {
        void* p = (void*)ws;
        ws += (bytes + 255) & ~(size_t)255;
        return p;
    };
    int*   bcnt = (int*)carve((size_t)nbkt * 4);
    int*   bbase= (int*)carve((size_t)(nbkt + 1) * 4);
    int*   bcur = (int*)carve((size_t)nbkt * 4);
    int2*  part = (int2*)carve((size_t)E * 8);
    int*   rowp = (int*)carve((size_t)(n + 1) * 4);
    float* dinv = (float*)carve((size_t)n * 4);
    int*   csr  = (int*)carve((size_t)E * 4);
    void*  bufA = carve((size_t)n * 64 * 4);      // fp32 x64 max use
    void*  bufB = carve((size_t)n * 64 * 4);
    void*  bufC = carve((size_t)n * 32 * 4);

    // ---- graph preprocessing ----
    zero_int_kernel<<<cdiv(nbkt, 256), 256, 0, stream>>>(bcnt, nbkt);
    bucket_count_kernel<<<256, 256, 0, stream>>>(dst, E, nbkt, bcnt);
    bucket_scan_kernel<<<1, 256, 0, stream>>>(bcnt, nbkt, bbase, bcur, rowp, n);
    pair_blocksort_kernel<<<cdiv(E, PS_CHUNK), 256, 0, stream>>>(src, dst, E, nbkt, bcur, part);
    bucket_csr_kernel<<<nbkt, 256, 0, stream>>>(part, bbase, n, rowp, dinv, csr);

    // ---- layer 1: 128 -> 64 (GEMM then aggregate), relu; H1s stored fp16 ----
    // H1s = dinv ⊙ (X We1)  [fp16];  B1 = relu(dinv ⊙ agg(H1s) + b)
    gemm_tile_kernel<128, 64, 64, false, false, true, true>
        <<<dim3(nrb, 1), 256, 0, stream>>>(x, We1, nullptr, dinv, bufA, n);
    aggregate_kernel<64, true, true, false, true>
        <<<nwv, 256, 0, stream>>>(bufA, rowp, csr, dinv, be1, (float*)bufB, n);

    // ---- layer 2: 64 -> 32 (GEMM then aggregate); output pre-scaled for L3 ----
    // H2s = dinv ⊙ (B1 We2);  Zs = dinv ⊙ (dinv ⊙ agg(H2s) + b)
    gemm_tile_kernel<64, 32, 32, false, false, true, false>
        <<<dim3(nrb, 1), 128, 0, stream>>>((const float*)bufB, We2, nullptr, dinv, bufA, n);
    aggregate_kernel<32, false, true, true, false>
        <<<nwv, 256, 0, stream>>>(bufA, rowp, csr, dinv, be2, (float*)bufC, n);

    // ---- layer 3: 32 -> 64 (aggregate FIRST, then GEMM), relu; Ds stored fp16 ----
    // A3 = dinv ⊙ agg(Zs)  (= S·Z);  Ds = dinv ⊙ relu(A3 Wd1 + b)  [fp16]
    aggregate_kernel<32, false, false, false, false>
        <<<nwv, 256, 0, stream>>>(bufC, rowp, csr, dinv, nullptr, (float*)bufA, n);
    gemm_tile_kernel<32, 64, 64, true, true, true, true>
        <<<dim3(nrb, 1), 256, 0, stream>>>((const float*)bufA, Wd1, bd1, dinv, bufB, n);

    // ---- layer 4: 64 -> 128 (aggregate FIRST, then GEMM) ----
    // A4 = dinv ⊙ agg(Ds)  (= S·D);  out = A4 Wd2 + b
    aggregate_kernel<64, false, false, false, true>
        <<<nwv, 256, 0, stream>>>(bufB, rowp, csr, dinv, nullptr, (float*)bufA, n);
    gemm_tile_kernel<64, 128, 64, true, false, false, false>
        <<<dim3(nrb, 2), 256, 0, stream>>>((const float*)bufA, Wd2, bd2, dinv, d_out, n);
}

// Round 8
// 197.939 us; speedup vs baseline: 1.9423x; 1.0878x over previous
//
#include <hip/hip_runtime.h>

typedef _Float16 half4 __attribute__((ext_vector_type(4)));

// ---------------- graph preprocessing (deterministic bucketed sort) ----------------
// Buckets of 64 consecutive dst nodes; chunks of 4096 edges.
// hist[chunk][bucket] histogram -> per-bucket scan across chunks -> deterministic
// scatter at precomputed offsets. NO contended global atomics anywhere.

static constexpr int NPB_SHIFT = 6;           // 64 nodes per bucket
static constexpr int NPB = 1 << NPB_SHIFT;
static constexpr int MAX_BKT = 1024;          // supports n <= 65536
static constexpr int PS_CHUNK = 4096;         // edges per chunk

// K1: per-chunk bucket histogram (LDS atomics only), coalesced global write
__global__ __launch_bounds__(256) void hist_kernel(const int* __restrict__ dst, int E,
                                                   int nbkt, int* __restrict__ hist) {
    __shared__ int lc[MAX_BKT];
    int tid = threadIdx.x;
    int b = blockIdx.x;
    int e0 = b * PS_CHUNK;
    int e1 = e0 + PS_CHUNK; if (e1 > E) e1 = E;
    for (int i = tid; i < nbkt; i += 256) lc[i] = 0;
    __syncthreads();
    for (int i = e0 + tid; i < e1; i += 256)
        atomicAdd(&lc[dst[i] >> NPB_SHIFT], 1);
    __syncthreads();
    for (int i = tid; i < nbkt; i += 256) hist[(size_t)b * nbkt + i] = lc[i];
}

// K2a: per-bucket exclusive scan across chunks (one wave per bucket), in place.
// hist[c][i] becomes the exclusive offset of chunk c within bucket i; bcnt[i] = total.
__global__ __launch_bounds__(256) void col_scan_kernel(int* __restrict__ hist, int nchunk,
                                                       int nbkt, int* __restrict__ bcnt) {
    int i = blockIdx.x * 4 + (threadIdx.x >> 6);
    if (i >= nbkt) return;
    int lane = threadIdx.x & 63;
    int run = 0;
    for (int c0 = 0; c0 < nchunk; c0 += 64) {
        int c = c0 + lane;
        int v = (c < nchunk) ? hist[(size_t)c * nbkt + i] : 0;
        int inc = v;
#pragma unroll
        for (int m = 1; m < 64; m <<= 1) {
            int u = __shfl_up(inc, m);
            if (lane >= m) inc += u;
        }
        if (c < nchunk) hist[(size_t)c * nbkt + i] = run + inc - v;
        run += __shfl(inc, 63);
    }
    if (lane == 0) bcnt[i] = run;
}

// K2b: single-block exclusive scan of bcnt -> bbase[0..nbkt]; rowp[n] = E
__global__ __launch_bounds__(256) void bucket_scan_kernel(const int* __restrict__ bcnt, int nbkt,
                                                          int* __restrict__ bbase,
                                                          int* __restrict__ rowp, int n) {
    __shared__ int wsum[4];
    int tid = threadIdx.x, lane = tid & 63, w = tid >> 6;
    int chunk = (nbkt + 255) / 256;
    int begin = tid * chunk;
    int end = begin + chunk; if (end > nbkt) end = nbkt;
    int s = 0;
    for (int i = begin; i < end; ++i) s += bcnt[i];
    int inc = s;
#pragma unroll
    for (int m = 1; m < 64; m <<= 1) {
        int u = __shfl_up(inc, m);
        if (lane >= m) inc += u;
    }
    if (lane == 63) wsum[w] = inc;
    __syncthreads();
    int off = 0;
    for (int i = 0; i < w; ++i) off += wsum[i];
    int run = off + inc - s;
    for (int i = begin; i < end; ++i) {
        bbase[i] = run;
        run += bcnt[i];
    }
    if (tid == 255) { bbase[nbkt] = run; rowp[n] = run; }   // run == E
}

// K3: per-chunk LDS bucket sort, write-out at deterministic precomputed offsets.
__global__ __launch_bounds__(256) void pair_blocksort_kernel(const int* __restrict__ src,
                                                             const int* __restrict__ dst,
                                                             int E, int nbkt,
                                                             const int* __restrict__ hist,
                                                             const int* __restrict__ bbase,
                                                             int2* __restrict__ part) {
    __shared__ int2 pairs[PS_CHUNK];          // 32 KB
    __shared__ int lbase[MAX_BKT];
    __shared__ int lcur[MAX_BKT];
    __shared__ int gpos[MAX_BKT];
    __shared__ int wsum[4];
    const int tid = threadIdx.x;
    const int b = blockIdx.x;
    const int e0 = b * PS_CHUNK;
    int e1 = e0 + PS_CHUNK; if (e1 > E) e1 = E;

    for (int i = tid; i < nbkt; i += 256) {
        lcur[i] = 0;
        gpos[i] = bbase[i] + hist[(size_t)b * nbkt + i];   // this chunk's exact slot
    }
    __syncthreads();
    // pass 1: count
    for (int i = e0 + tid; i < e1; i += 256)
        atomicAdd(&lcur[dst[i] >> NPB_SHIFT], 1);
    __syncthreads();
    // scan counters: 256 threads x 4 buckets
    {
        int b0 = tid * 4;
        int v[4]; int s = 0;
#pragma unroll
        for (int k = 0; k < 4; ++k) {
            int bb = b0 + k;
            v[k] = (bb < nbkt) ? lcur[bb] : 0;
            s += v[k];
        }
        int lane = tid & 63, w = tid >> 6;
        int inc = s;
#pragma unroll
        for (int m = 1; m < 64; m <<= 1) {
            int u = __shfl_up(inc, m);
            if (lane >= m) inc += u;
        }
        if (lane == 63) wsum[w] = inc;
        __syncthreads();
        int off = 0;
        for (int i = 0; i < w; ++i) off += wsum[i];
        int run = off + inc - s;
        __syncthreads();
#pragma unroll
        for (int k = 0; k < 4; ++k) {
            int bb = b0 + k;
            if (bb < nbkt) { lbase[bb] = run; lcur[bb] = run; }
            run += v[k];
        }
    }
    __syncthreads();
    // pass 2: scatter into bucket-sorted LDS order (dst/src re-read, L2-hot)
    for (int i = e0 + tid; i < e1; i += 256) {
        int s = src[i], d = dst[i];
        int p = atomicAdd(&lcur[d >> NPB_SHIFT], 1);
        pairs[p] = make_int2(s, d);
    }
    __syncthreads();
    // write out: consecutive LDS slots in a bucket -> consecutive global slots
    const int cnt = e1 - e0;
    for (int i = tid; i < cnt; i += 256) {
        int2 pr = pairs[i];
        int bk = pr.y >> NPB_SHIFT;
        part[gpos[bk] + (i - lbase[bk])] = pr;
    }
}

// K5: one block per bucket: per-node counts (LDS), wave scan -> rowp/dinv,
// then localized scatter of csr within the block-exclusive region.
__global__ __launch_bounds__(256) void bucket_csr_kernel(const int2* __restrict__ part,
                                                         const int* __restrict__ bbase, int n,
                                                         int* __restrict__ rowp,
                                                         float* __restrict__ dinv,
                                                         int* __restrict__ csr) {
    __shared__ int lcnt[NPB];
    int b = blockIdx.x, tid = threadIdx.x;
    int node0 = b << NPB_SHIFT;
    int nloc = n - node0; if (nloc > NPB) nloc = NPB;
    int p0 = bbase[b], p1 = bbase[b + 1];
    if (tid < NPB) lcnt[tid] = 0;
    __syncthreads();
    for (int i = p0 + tid; i < p1; i += 256)
        atomicAdd(&lcnt[part[i].y & (NPB - 1)], 1);
    __syncthreads();
    if (tid < 64) {                       // wave 0: scan 64 counters
        int c = lcnt[tid];
        int inc = c;
#pragma unroll
        for (int m = 1; m < 64; m <<= 1) {
            int u = __shfl_up(inc, m);
            if (tid >= m) inc += u;
        }
        int base = p0 + inc - c;
        if (tid < nloc) {
            rowp[node0 + tid] = base;
            dinv[node0 + tid] = rsqrtf((float)(c + 1));    // +1 self-loop
        }
        lcnt[tid] = base;                 // becomes the scatter cursor
    }
    __syncthreads();
    for (int i = p0 + tid; i < p1; i += 256) {
        int2 pr = part[i];
        int pos = atomicAdd(&lcnt[pr.y & (NPB - 1)], 1);
        csr[pos] = pr.x;
    }
}

// ---------------- per-layer kernels ----------------

template <bool HALF>
__device__ __forceinline__ float4 ldrow4(const void* H, size_t off) {
    if constexpr (HALF) {
        half4 h = *reinterpret_cast<const half4*>(reinterpret_cast<const _Float16*>(H) + off);
        return make_float4((float)h.x, (float)h.y, (float)h.z, (float)h.w);
    } else {
        return *reinterpret_cast<const float4*>(reinterpret_cast<const float*>(H) + off);
    }
}

template <bool HALF>
__device__ __forceinline__ void strow4(void* H, size_t off, float4 o) {
    if constexpr (HALF) {
        half4 hv;
        hv.x = (_Float16)o.x; hv.y = (_Float16)o.y;
        hv.z = (_Float16)o.z; hv.w = (_Float16)o.w;
        *reinterpret_cast<half4*>(reinterpret_cast<_Float16*>(H) + off) = hv;
    } else {
        *reinterpret_cast<float4*>(reinterpret_cast<float*>(H) + off) = o;
    }
}

// Block-tiled GEMM: H[r][c] = epi(sum_k X[r][k] W[k][c])
// epi: +bias (BIAS), relu (RELU), * dinv[r] (SCALE); in/out fp32 or fp16.
template <int K, int OUT, int BN, bool BIAS, bool RELU, bool SCALE, bool HALF_IN, bool HALF_OUT>
__global__ __launch_bounds__(16 * (BN / 4)) void gemm_tile_kernel(
        const void* __restrict__ X, const float* __restrict__ W,
        const float* __restrict__ bias, const float* __restrict__ dinv,
        void* __restrict__ Hout, int n) {
    constexpr int BM = 64;
    constexpr int KB = (K > 64) ? 64 : K;
    constexpr int NTHR = 16 * (BN / 4);
    constexpr int KV = KB / 4;              // 4-elem groups per A row chunk

    __shared__ float At[KB][BM + 4];        // [k][r], stride 68 floats
    __shared__ float Bl[K][BN];

    const int tid = threadIdx.x;
    const int tx = tid % (BN / 4);
    const int ty = tid / (BN / 4);
    const int rb = blockIdx.x * BM;
    const int co = blockIdx.y * BN;

    // load B panel (W[:, co:co+BN]) once
    for (int i = tid; i < K * BN / 4; i += NTHR) {
        int k = i / (BN / 4);
        int c0 = (i % (BN / 4)) * 4;
        *reinterpret_cast<float4*>(&Bl[k][c0]) =
            *reinterpret_cast<const float4*>(&W[(size_t)k * OUT + co + c0]);
    }

    float acc[4][4] = {};

#pragma unroll
    for (int ch = 0; ch < K / KB; ++ch) {
        if (ch) __syncthreads();            // previous chunk's readers done
        // stage A chunk transposed
        for (int i = tid; i < BM * KV; i += NTHR) {
            int r = i / KV;
            int k0 = (i % KV) * 4;
            int rg = rb + r; if (rg > n - 1) rg = n - 1;     // clamp tail
            float4 xv = ldrow4<HALF_IN>(X, (size_t)rg * K + ch * KB + k0);
            At[k0 + 0][r] = xv.x;
            At[k0 + 1][r] = xv.y;
            At[k0 + 2][r] = xv.z;
            At[k0 + 3][r] = xv.w;
        }
        __syncthreads();

#pragma unroll 8
        for (int k = 0; k < KB; ++k) {
            float4 a = *reinterpret_cast<const float4*>(&At[k][ty * 4]);
            float4 b = *reinterpret_cast<const float4*>(&Bl[ch * KB + k][tx * 4]);
            acc[0][0] = fmaf(a.x, b.x, acc[0][0]); acc[0][1] = fmaf(a.x, b.y, acc[0][1]);
            acc[0][2] = fmaf(a.x, b.z, acc[0][2]); acc[0][3] = fmaf(a.x, b.w, acc[0][3]);
            acc[1][0] = fmaf(a.y, b.x, acc[1][0]); acc[1][1] = fmaf(a.y, b.y, acc[1][1]);
            acc[1][2] = fmaf(a.y, b.z, acc[1][2]); acc[1][3] = fmaf(a.y, b.w, acc[1][3]);
            acc[2][0] = fmaf(a.z, b.x, acc[2][0]); acc[2][1] = fmaf(a.z, b.y, acc[2][1]);
            acc[2][2] = fmaf(a.z, b.z, acc[2][2]); acc[2][3] = fmaf(a.z, b.w, acc[2][3]);
            acc[3][0] = fmaf(a.w, b.x, acc[3][0]); acc[3][1] = fmaf(a.w, b.y, acc[3][1]);
            acc[3][2] = fmaf(a.w, b.z, acc[3][2]); acc[3][3] = fmaf(a.w, b.w, acc[3][3]);
        }
    }

    float4 bv = make_float4(0.f, 0.f, 0.f, 0.f);
    if (BIAS) bv = *reinterpret_cast<const float4*>(&bias[co + tx * 4]);
    int r0 = rb + ty * 4;
#pragma unroll
    for (int i = 0; i < 4; ++i) {
        int r = r0 + i;
        if (r < n) {
            float4 o;
            o.x = acc[i][0]; o.y = acc[i][1]; o.z = acc[i][2]; o.w = acc[i][3];
            if (BIAS) { o.x += bv.x; o.y += bv.y; o.z += bv.z; o.w += bv.w; }
            if (RELU) {
                o.x = fmaxf(o.x, 0.f); o.y = fmaxf(o.y, 0.f);
                o.z = fmaxf(o.z, 0.f); o.w = fmaxf(o.w, 0.f);
            }
            if (SCALE) {
                float dv = dinv[r];
                o.x *= dv; o.y *= dv; o.z *= dv; o.w *= dv;
            }
            strow4<HALF_OUT>(Hout, (size_t)r * OUT + co + tx * 4, o);
        }
    }
}

// One wave per node. Lanes split into EG = 64/(C/4) edge groups; each lane covers
// 4 channels; 4-deep unrolled gather pipeline. Cross-group shfl_xor reduce.
// o = dinv[d]*(H[d]+sum H[s]); if BIAS o += b; if RELU relu; if POST o *= dinv[d].
template <int C, bool RELU, bool HAS_BIAS, bool POST_SCALE, bool HALF_IN, bool HALF_OUT>
__global__ __launch_bounds__(256) void aggregate_kernel(const void* __restrict__ H,
                                                        const int* __restrict__ row,
                                                        const int* __restrict__ csr_src,
                                                        const float* __restrict__ dinv,
                                                        const float* __restrict__ bias,
                                                        void* __restrict__ Y, int n) {
    constexpr int LPN = C / 4;        // lanes covering one row: 8 / 16
    constexpr int EG = 64 / LPN;      // edge groups: 8 / 4
    int wid = (blockIdx.x * blockDim.x + threadIdx.x) >> 6;
    if (wid >= n) return;             // wave-uniform exit
    int lane = threadIdx.x & 63;
    int g = lane / LPN;
    int c0 = (lane % LPN) * 4;
    const int node = wid;

    float4 a0 = make_float4(0.f, 0.f, 0.f, 0.f);
    float4 a1 = a0, a2 = a0, a3 = a0;
    if (g == 0) a0 = ldrow4<HALF_IN>(H, (size_t)node * C + c0);   // self-loop
    int e = row[node] + g;
    int end = row[node + 1];
    for (; e + 3 * EG < end; e += 4 * EG) {
        int s0 = csr_src[e];
        int s1 = csr_src[e + EG];
        int s2 = csr_src[e + 2 * EG];
        int s3 = csr_src[e + 3 * EG];
        float4 h0 = ldrow4<HALF_IN>(H, (size_t)s0 * C + c0);
        float4 h1 = ldrow4<HALF_IN>(H, (size_t)s1 * C + c0);
        float4 h2 = ldrow4<HALF_IN>(H, (size_t)s2 * C + c0);
        float4 h3 = ldrow4<HALF_IN>(H, (size_t)s3 * C + c0);
        a0.x += h0.x; a0.y += h0.y; a0.z += h0.z; a0.w += h0.w;
        a1.x += h1.x; a1.y += h1.y; a1.z += h1.z; a1.w += h1.w;
        a2.x += h2.x; a2.y += h2.y; a2.z += h2.z; a2.w += h2.w;
        a3.x += h3.x; a3.y += h3.y; a3.z += h3.z; a3.w += h3.w;
    }
    for (; e < end; e += EG) {
        int s = csr_src[e];
        float4 hv = ldrow4<HALF_IN>(H, (size_t)s * C + c0);
        a0.x += hv.x; a0.y += hv.y; a0.z += hv.z; a0.w += hv.w;
    }
    float4 acc;
    acc.x = (a0.x + a1.x) + (a2.x + a3.x);
    acc.y = (a0.y + a1.y) + (a2.y + a3.y);
    acc.z = (a0.z + a1.z) + (a2.z + a3.z);
    acc.w = (a0.w + a1.w) + (a2.w + a3.w);
#pragma unroll
    for (int m = LPN; m < 64; m <<= 1) {
        acc.x += __shfl_xor(acc.x, m);
        acc.y += __shfl_xor(acc.y, m);
        acc.z += __shfl_xor(acc.z, m);
        acc.w += __shfl_xor(acc.w, m);
    }
    if (g == 0) {
        float dv = dinv[node];
        float4 o;
        o.x = acc.x * dv; o.y = acc.y * dv; o.z = acc.z * dv; o.w = acc.w * dv;
        if (HAS_BIAS) {
            o.x += bias[c0 + 0]; o.y += bias[c0 + 1];
            o.z += bias[c0 + 2]; o.w += bias[c0 + 3];
        }
        if (RELU) {
            o.x = fmaxf(o.x, 0.f); o.y = fmaxf(o.y, 0.f);
            o.z = fmaxf(o.z, 0.f); o.w = fmaxf(o.w, 0.f);
        }
        if (POST_SCALE) { o.x *= dv; o.y *= dv; o.z *= dv; o.w *= dv; }
        strow4<HALF_OUT>(Y, (size_t)node * C + c0, o);
    }
}

// ---------------- host launch ----------------

static inline int cdiv(int a, int b) { return (a + b - 1) / b; }

extern "C" void kernel_launch(void* const* d_in, const int* in_sizes, int n_in,
                              void* d_out, int out_size, void* d_ws, size_t ws_size,
                              hipStream_t stream) {
    const float* x   = (const float*)d_in[0];
    const int*   ei  = (const int*)d_in[1];
    const float* We1 = (const float*)d_in[2];
    const float* be1 = (const float*)d_in[3];
    const float* We2 = (const float*)d_in[4];
    const float* be2 = (const float*)d_in[5];
    const float* Wd1 = (const float*)d_in[6];
    const float* bd1 = (const float*)d_in[7];
    const float* Wd2 = (const float*)d_in[8];
    const float* bd2 = (const float*)d_in[9];

    const int n = in_sizes[0] / 128;
    const int E = in_sizes[1] / 2;
    const int* src = ei;
    const int* dst = ei + E;
    const int nbkt = cdiv(n, NPB);
    const int nchunk = cdiv(E, PS_CHUNK);
    const int nrb = cdiv(n, 64);
    const int nwv = cdiv(n * 64, 256);      // one wave per node

    // carve workspace (256B aligned)
    char* ws = (char*)d_ws;
    auto carve = [&](size_t bytes) -> void* {
        void* p = (void*)ws;
        ws += (bytes + 255) & ~(size_t)255;
        return p;
    };
    int*   hist = (int*)carve((size_t)nchunk * nbkt * 4);
    int*   bcnt = (int*)carve((size_t)nbkt * 4);
    int*   bbase= (int*)carve((size_t)(nbkt + 1) * 4);
    int2*  part = (int2*)carve((size_t)E * 8);
    int*   rowp = (int*)carve((size_t)(n + 1) * 4);
    float* dinv = (float*)carve((size_t)n * 4);
    int*   csr  = (int*)carve((size_t)E * 4);
    void*  bufA = carve((size_t)n * 64 * 4);
    void*  bufB = carve((size_t)n * 64 * 4);
    void*  bufC = carve((size_t)n * 32 * 4);

    // ---- graph preprocessing (deterministic, no contended atomics) ----
    hist_kernel<<<nchunk, 256, 0, stream>>>(dst, E, nbkt, hist);
    col_scan_kernel<<<cdiv(nbkt, 4), 256, 0, stream>>>(hist, nchunk, nbkt, bcnt);
    bucket_scan_kernel<<<1, 256, 0, stream>>>(bcnt, nbkt, bbase, rowp, n);
    pair_blocksort_kernel<<<nchunk, 256, 0, stream>>>(src, dst, E, nbkt, hist, bbase, part);
    bucket_csr_kernel<<<nbkt, 256, 0, stream>>>(part, bbase, n, rowp, dinv, csr);

    // ---- layer 1: 128 -> 64 (GEMM then aggregate), relu; all intermediates fp16 ----
    // H1s = dinv ⊙ (X We1)  [fp16];  B1 = relu(dinv ⊙ agg(H1s) + b)  [fp16]
    gemm_tile_kernel<128, 64, 64, false, false, true, false, true>
        <<<dim3(nrb, 1), 256, 0, stream>>>(x, We1, nullptr, dinv, bufA, n);
    aggregate_kernel<64, true, true, false, true, true>
        <<<nwv, 256, 0, stream>>>(bufA, rowp, csr, dinv, be1, bufB, n);

    // ---- layer 2: 64 -> 32 (GEMM then aggregate); output pre-scaled for L3 ----
    // H2s = dinv ⊙ (B1 We2)  [fp16];  Zs = dinv ⊙ (dinv ⊙ agg(H2s) + b)  [fp16]
    gemm_tile_kernel<64, 32, 32, false, false, true, true, true>
        <<<dim3(nrb, 1), 128, 0, stream>>>(bufB, We2, nullptr, dinv, bufA, n);
    aggregate_kernel<32, false, true, true, true, true>
        <<<nwv, 256, 0, stream>>>(bufA, rowp, csr, dinv, be2, bufC, n);

    // ---- layer 3: 32 -> 64 (aggregate FIRST, then GEMM), relu; pre-scaled for L4 ----
    // A3 = dinv ⊙ agg(Zs)  [fp16];  Ds = dinv ⊙ relu(A3 Wd1 + b)  [fp16]
    aggregate_kernel<32, false, false, false, true, true>
        <<<nwv, 256, 0, stream>>>(bufC, rowp, csr, dinv, nullptr, bufA, n);
    gemm_tile_kernel<32, 64, 64, true, true, true, true, true>
        <<<dim3(nrb, 1), 256, 0, stream>>>(bufA, Wd1, bd1, dinv, bufB, n);

    // ---- layer 4: 64 -> 128 (aggregate FIRST, then GEMM) ----
    // A4 = dinv ⊙ agg(Ds)  [fp16];  out = A4 Wd2 + b  [fp32]
    aggregate_kernel<64, false, false, false, true, true>
        <<<nwv, 256, 0, stream>>>(bufB, rowp, csr, dinv, nullptr, bufA, n);
    gemm_tile_kernel<64, 128, 64, true, false, false, true, false>
        <<<dim3(nrb, 2), 256, 0, stream>>>(bufA, Wd2, bd2, dinv, d_out, n);
}